// Round 7
// baseline (316.404 us; speedup 1.0000x reference)
//
#include <hip/hip_runtime.h>
#include <stdint.h>

// GAT encoder: 3 GAT layers + masked global max pool.
// fp16-storage pipeline (threshold 2% relative; r16 absmax 9.8e-4).
// r17: GEMM 1D-grid XCD-affinity swizzle, launch_bounds(.,4), MPAD 20480.
// r18 FAILED (+43us): per-group runtime predication serialized gather issue.
// r19 WIN (-19us): uint4 gather, unconditional batches, wave-uniform {32,16}.
// r20 FAILED (+25us): 8-way switch bloated code, VGPR 32->44, occ 66->46.
// r21 FAILED (+9us): byte-offset LDS word broke addr-fold, VGPR 32->36.
// r22: revert to r19. r23 WIN (-12us): two nodes/wave in k_agg (prologue
// amortized x2, one less shfl level, wave count halved). k_agg now below the
// harness 44us fill in top-5 -> plateaued; DO NOT touch its gather loop.
// r24: GEMM BK 32->64. Halves k-steps (K=512: 16->8 barriers+vmcnt drains,
// the known structural stall). LDS 32KB/block, still 4 blocks/CU at
// launch_bounds(256,4). MFMA gains ksub x2 sub-loop; staging stays
// global_load_lds width=16 coalesced.

#define NN 20000
#define MPAD 20480
#define NE 320000
#define NBATCH 16
#define NEG 0.2f
#define WSCALE 64.0f
#define WINV 0.015625f

using f16x8 = __attribute__((ext_vector_type(8))) _Float16;
using f32x4 = __attribute__((ext_vector_type(4))) float;
using h2 = __attribute__((ext_vector_type(2))) _Float16;

#define GLL16(gp, lp)                                                        \
  __builtin_amdgcn_global_load_lds(                                          \
      (const __attribute__((address_space(1))) void*)(gp),                   \
      (__attribute__((address_space(3))) void*)(lp), 16, 0, 0)

static __device__ __forceinline__ unsigned short h2u(_Float16 h) {
  union { _Float16 f; unsigned short u; } c;
  c.f = h;
  return c.u;
}
static __device__ __forceinline__ float u2f(unsigned short u) {
  union { unsigned short u; _Float16 f; } c;
  c.u = u;
  return (float)c.f;
}
static __device__ __forceinline__ h2 bits2h2(unsigned v) {
  union { unsigned u; h2 h; } c;
  c.u = v;
  return c.h;
}
static __device__ __forceinline__ unsigned h22bits(h2 h) {
  union { h2 h; unsigned u; } c;
  c.h = h;
  return c.u;
}
static __device__ __forceinline__ unsigned encf(float f) {
  unsigned u = __float_as_uint(f);
  return (u & 0x80000000u) ? ~u : (u | 0x80000000u);
}
static __device__ __forceinline__ float decf(unsigned u) {
  return __uint_as_float((u & 0x80000000u) ? (u ^ 0x80000000u) : ~u);
}

// -------- fused init+prep: deg/enc/flag/alpha-zero + W->fp16^T + x->fp16 ----
#define R1 (512 * 128)
#define R2 (512 * 512)
#define R3 (128 * 512)
#define PREPTOT (R1 + R2 + R3 + NN * 128)
__global__ void k_init_prep(const float* __restrict__ W1, const float* __restrict__ W2,
                            const float* __restrict__ W3, const float* __restrict__ x,
                            unsigned short* __restrict__ wt1,
                            unsigned short* __restrict__ wt2,
                            unsigned short* __restrict__ wt3,
                            unsigned short* __restrict__ xp, int* deg,
                            unsigned* enc, int* flag, float* alz, int alcount) {
  int idx = blockIdx.x * blockDim.x + threadIdx.x;
  if (idx < R1) {
    int n = idx & 511, k = idx >> 9;  // W1 [128][512]
    wt1[(size_t)n * 128 + k] = h2u((_Float16)(W1[(size_t)k * 512 + n] * WSCALE));
  } else if (idx < R1 + R2) {
    int j = idx - R1;
    int n = j & 511, k = j >> 9;  // W2 [512][512]
    wt2[(size_t)n * 512 + k] = h2u((_Float16)(W2[(size_t)k * 512 + n] * WSCALE));
  } else if (idx < R1 + R2 + R3) {
    int j = idx - (R1 + R2);
    int n = j & 127, k = j >> 7;  // W3 [512][128]
    wt3[(size_t)n * 512 + k] = h2u((_Float16)(W3[(size_t)k * 128 + n] * WSCALE));
  } else if (idx < PREPTOT) {
    int j = idx - (R1 + R2 + R3);
    xp[j] = h2u((_Float16)x[j]);
  }
  if (idx < NN) deg[idx] = 1;  // self loop
  if (idx < NBATCH * 128) enc[idx] = ~__float_as_uint(-1e30f);  // encf(-1e30)
  if (idx == 0) *flag = 0;
  if (idx < alcount) alz[idx] = 0.f;
}

__global__ void k_count(const int* __restrict__ ei, int* __restrict__ deg) {
  int e = blockIdx.x * blockDim.x + threadIdx.x;
  if (e < NE) atomicAdd(&deg[ei[NE + e]], 1);
}

__global__ void k_scan(const int* __restrict__ deg, int* __restrict__ row_ptr,
                       int* __restrict__ cursor) {
  __shared__ int wsum[16];
  int t = threadIdx.x;  // 1024 threads
  int lane = t & 63, wid = t >> 6;
  const int CH = 20;
  int beg = t * CH;
  int s = 0;
  for (int i = 0; i < CH; i++) {
    int idx = beg + i;
    if (idx < NN) s += deg[idx];
  }
  int incl = s;
  for (int off = 1; off < 64; off <<= 1) {
    int v = __shfl_up(incl, off, 64);
    if (lane >= off) incl += v;
  }
  if (lane == 63) wsum[wid] = incl;
  __syncthreads();
  if (t < 16) {
    int v = wsum[t];
    int in2 = v;
    for (int off = 1; off < 16; off <<= 1) {
      int u = __shfl_up(in2, off, 16);
      if (t >= off) in2 += u;
    }
    wsum[t] = in2 - v;  // exclusive wave base
  }
  __syncthreads();
  int run = wsum[wid] + incl - s;
  for (int i = 0; i < CH; i++) {
    int idx = beg + i;
    if (idx < NN) {
      row_ptr[idx] = run;
      cursor[idx] = run;
      run += deg[idx];
    }
  }
  if (t == 1023) row_ptr[NN] = run;
}

__global__ void k_fill(const int* __restrict__ ei, int* __restrict__ cursor,
                       int* __restrict__ col, const int* __restrict__ nmask,
                       int* __restrict__ flag) {
  int i = blockIdx.x * blockDim.x + threadIdx.x;
  if (i >= NE + NN) return;
  int src, dst;
  if (i < NE) {
    src = ei[i];
    dst = ei[NE + i];
  } else {
    src = dst = i - NE;
    if (nmask[src] != 0) *flag = 1;
  }
  int pos = atomicAdd(&cursor[dst], 1);
  col[pos] = src;
}

// ---------------- GEMM: fp16 x fp16 -> fp16 C, fp32 acc, alpha fused --------
// Swapped mfma operands: thread (lquad,lrow) reg r holds C[m=lrow][n=lquad*4+r].
// SWIZ: 1D grid, id%8 == (bm-block)%8 -> one XCD owns each A row-block (A
// fetched once into its L2; 4 bn-variants share it). Staging via
// global_load_lds width=16. BK=64: 8 slots (16B each) per row; ksub x2 MFMA.
#define BN 128
#define BK 64

template <int BMT, int NT, bool SWIZ>
__global__ __launch_bounds__(NT, 4) void k_gemm(
    const unsigned short* __restrict__ Ap, const unsigned short* __restrict__ Wt,
    unsigned short* __restrict__ C, const float* __restrict__ attS,
    const float* __restrict__ attD, float* __restrict__ alS,
    float* __restrict__ alD, int K, int Nc, int H) {
  __shared__ __align__(16) unsigned short As[BMT][BK];
  __shared__ __align__(16) unsigned short Bs[BN][BK];
  int tid = threadIdx.x;
  int bm, bn;
  if constexpr (SWIZ) {
    int id = blockIdx.x;        // NBX=4: id = r + 8*(bn_i + 4*q), bm_row = q*8+r
    int r = id & 7, t = id >> 3;
    bn = (t & 3) * BN;
    bm = (((t >> 2) << 3) + r) * BMT;
  } else {
    bm = blockIdx.y * BMT;
    bn = blockIdx.x * BN;
  }
  int wid = tid >> 6, lane = tid & 63;
  int wm = (BMT == 128) ? (wid >> 1) * 64 : 0;
  int wn = (BMT == 128) ? (wid & 1) * 64 : wid * 64;
  int lrow = lane & 15, lquad = lane >> 4;

  f32x4 acc[4][4] = {};

  for (int k0 = 0; k0 < K; k0 += BK) {
    __syncthreads();
#pragma unroll
    for (int i = 0; i < (BMT * 8) / NT; i++) {
      int slot = tid + NT * i;
      int row = slot >> 3;
      int ks = (slot & 7) * 8;
      GLL16(Ap + (size_t)(bm + row) * K + k0 + ks, &As[0][0] + (size_t)slot * 8);
    }
#pragma unroll
    for (int i = 0; i < (BN * 8) / NT; i++) {
      int slot = tid + NT * i;
      int row = slot >> 3;
      int ks = (slot & 7) * 8;
      GLL16(Wt + (size_t)(bn + row) * K + k0 + ks, &Bs[0][0] + (size_t)slot * 8);
    }
    __syncthreads();

#pragma unroll
    for (int ksub = 0; ksub < 2; ksub++) {
      f16x8 af[4];
#pragma unroll
      for (int mf = 0; mf < 4; mf++)
        af[mf] = *(const f16x8*)&As[wm + mf * 16 + lrow][ksub * 32 + lquad * 8];
#pragma unroll
      for (int nf = 0; nf < 4; nf++) {
        f16x8 bf = *(const f16x8*)&Bs[wn + nf * 16 + lrow][ksub * 32 + lquad * 8];
#pragma unroll
        for (int mf = 0; mf < 4; mf++)
          acc[mf][nf] =
              __builtin_amdgcn_mfma_f32_16x16x32_f16(bf, af[mf], acc[mf][nf], 0, 0, 0);
      }
    }
  }
  // undo the x64 W scale
#pragma unroll
  for (int mf = 0; mf < 4; mf++)
#pragma unroll
    for (int nf = 0; nf < 4; nf++)
#pragma unroll
      for (int r = 0; r < 4; r++) acc[mf][nf][r] *= WINV;

  // fused alpha (this block's 128 cols == one head)
  float4 aS[4], aD[4];
#pragma unroll
  for (int nf = 0; nf < 4; nf++) {
    int n0 = bn + wn + nf * 16 + lquad * 4;
    aS[nf] = *(const float4*)(attS + n0);
    aD[nf] = *(const float4*)(attD + n0);
  }
  int head = bn >> 7;
#pragma unroll
  for (int mf = 0; mf < 4; mf++) {
    float ps = 0.f, pd = 0.f;
#pragma unroll
    for (int nf = 0; nf < 4; nf++) {
      ps += acc[mf][nf][0] * aS[nf].x + acc[mf][nf][1] * aS[nf].y +
            acc[mf][nf][2] * aS[nf].z + acc[mf][nf][3] * aS[nf].w;
      pd += acc[mf][nf][0] * aD[nf].x + acc[mf][nf][1] * aD[nf].y +
            acc[mf][nf][2] * aD[nf].z + acc[mf][nf][3] * aD[nf].w;
    }
    ps += __shfl_xor(ps, 16, 64);
    ps += __shfl_xor(ps, 32, 64);
    pd += __shfl_xor(pd, 16, 64);
    pd += __shfl_xor(pd, 32, 64);
    int row = bm + wm + mf * 16 + lrow;
    if (lquad == 0) {
      atomicAdd(&alS[(size_t)row * H + head], ps);
      atomicAdd(&alD[(size_t)row * H + head], pd);
    }
  }
  // C store: one 8B ushort4 per (mf,nf)
#pragma unroll
  for (int mf = 0; mf < 4; mf++) {
    int m = bm + wm + mf * 16 + lrow;
#pragma unroll
    for (int nf = 0; nf < 4; nf++) {
      int n0 = bn + wn + nf * 16 + lquad * 4;
      ushort4 o;
      o.x = h2u((_Float16)acc[mf][nf][0]);
      o.y = h2u((_Float16)acc[mf][nf][1]);
      o.z = h2u((_Float16)acc[mf][nf][2]);
      o.w = h2u((_Float16)acc[mf][nf][3]);
      *(ushort4*)(C + (size_t)m * Nc + n0) = o;
    }
  }
}

// Unconditional gather batch: NG groups of {2 edge slots x 2 node halves},
// uint4 per lane. LDS slots pre-zero-padded (32/node) so overshoot is safe.
// Structure kept identical to the proven r19 body (index-multiply address).
template <int HF, int NG>
static __device__ __forceinline__ void gat_gather(
    const unsigned long long* __restrict__ cwp, int je, int se,
    const unsigned short* __restrict__ hb, h2& ha0, h2& ha1, h2& ha2, h2& ha3) {
  unsigned long long q[NG];
  uint4 v[NG];
#pragma unroll
  for (int r = 0; r < NG; r++) q[r] = cwp[je + se + 2 * r];
#pragma unroll
  for (int r = 0; r < NG; r++)
    v[r] = *(const uint4*)(hb + (size_t)(unsigned)q[r] * HF);
#pragma unroll
  for (int r = 0; r < NG; r++) {
    h2 hw = bits2h2((unsigned)(q[r] >> 32));
    ha0 += hw * bits2h2(v[r].x);
    ha1 += hw * bits2h2(v[r].y);
    ha2 += hw * bits2h2(v[r].z);
    ha3 += hw * bits2h2(v[r].w);
  }
}

// ---------------- softmax + aggregate: 2 nodes/wave, 1 head/wave ------------
// PIN=true (H=4): sub = blockIdx&3 -> head s on XCDs {s, s+4}.
// Wave = 2 nodes x 1 head. Lanes: ns = lane>>5 (node half), sl = lane&31.
// Gather: 16 feature-lanes x uint4; 2 edge slots per node -> 4 loads/group.
// Wave-uniform two-tier granularity on cntu = max(cntA, cntB): 8 groups
// (16 edges/node) while rem>8, else 4 groups (8 edges/node); all batches
// unconditional. Fast path (both deg<=32): unnormalized t, scale by 1/S after
// the 2-slot merge. Reductions use xor offsets <=16 (stay within each half).
template <int H, bool RELU, bool FP16OUT, bool PIN>
__global__ __launch_bounds__(256) void k_agg(
    const unsigned short* __restrict__ h, const float* __restrict__ as_,
    const float* __restrict__ ad_, const int* __restrict__ row_ptr,
    const int* __restrict__ col, const float* __restrict__ bias,
    float* __restrict__ out, unsigned short* __restrict__ outp) {
  constexpr int HF = H * 128;
  __shared__ unsigned long long cw[4][2][32];
  int tid = threadIdx.x, bwid = tid >> 6, lane = tid & 63;
  int ns = lane >> 5, sl = lane & 31;
  int node, sub;
  if constexpr (PIN) {
    sub = blockIdx.x & 3;
    node = (blockIdx.x >> 2) * 8 + bwid * 2 + ns;  // grid = NN/2, NN%8==0
  } else {
    node = blockIdx.x * 8 + bwid * 2 + ns;  // grid = NN/8 exact
    sub = 0;
  }
  if (node >= NN) node = NN - 1;  // never taken (grids exact); keeps wave whole
  int beg = row_ptr[node], end = row_ptr[node + 1];
  int deg = end - beg;
  int degmax = max(deg, __shfl_xor(deg, 32, 64));  // wave-uniform
  bool fast = (degmax <= 32);
  float adv = ad_[(size_t)node * H + sub];
  float shift = (adv > 0.f) ? adv : NEG * adv;  // per-node surrogate max
  float fscale = 1.f;

  if (__builtin_expect(fast, 1)) {
    unsigned sidx = 0;
    float t = 0.f;
    if (sl < deg) {
      sidx = (unsigned)col[beg + sl];
      float e = as_[(size_t)sidx * H + sub] + adv;
      e = (e > 0.f) ? e : NEG * e;
      t = fminf(__expf(e - shift), 60000.f);  // f16-range guard
    }
    _Float16 ht = (_Float16)t;
    h2 hv;
    hv[0] = ht;
    hv[1] = ht;
    cw[bwid][ns][sl] = ((unsigned long long)h22bits(hv) << 32) | sidx;
    float S = t;  // per-half sum reduce (offsets <=16 stay within half)
#pragma unroll
    for (int off = 16; off; off >>= 1) S += __shfl_xor(S, off, 64);
    fscale = 1.f / S;
  }
  float Mr = 0.f, Sinv = 0.f;
  if (!fast) {  // rare general path: per-half online softmax
    float m = -1e30f, s = 0.f;
    for (int j = beg + sl; j < end; j += 32) {
      int sidx = col[j];
      float e = as_[(size_t)sidx * H + sub] + adv;
      e = (e > 0.f) ? e : NEG * e;
      float nm = fmaxf(m, e);
      s = s * __expf(m - nm) + __expf(e - nm);
      m = nm;
    }
    float mm = m;
#pragma unroll
    for (int off = 16; off; off >>= 1) mm = fmaxf(mm, __shfl_xor(mm, off, 64));
    float t = s * __expf(m - mm);
#pragma unroll
    for (int off = 16; off; off >>= 1) t += __shfl_xor(t, off, 64);
    Mr = mm;
    Sinv = 1.f / t;
  }

  const int se = (lane >> 4) & 1;                // edge slot 0..1 within node
  const int fb = sub * 128 + (lane & 15) * 8;    // 8 features/lane
  const unsigned short* __restrict__ hb = h + fb;
  float facc[8] = {0.f, 0.f, 0.f, 0.f, 0.f, 0.f, 0.f, 0.f};
  int nchunk = fast ? 1 : ((degmax + 31) >> 5);  // wave-uniform
  for (int ch = 0; ch < nchunk; ch++) {
    int c0 = beg + ch * 32;
    int cnt = end - c0;                 // per-half; may be <=0 when exhausted
    cnt = (cnt > 32) ? 32 : cnt;
    if (!fast) {  // refill normalized weights; zero-pad all 32 slots
      unsigned sidx = 0;
      float w = 0.f;
      if (sl < cnt) {
        sidx = (unsigned)col[c0 + sl];
        float e = as_[(size_t)sidx * H + sub] + adv;
        e = (e > 0.f) ? e : NEG * e;
        w = __expf(e - Mr) * Sinv;
      }
      _Float16 hw = (_Float16)w;
      h2 hv;
      hv[0] = hw;
      hv[1] = hw;
      cw[bwid][ns][sl] = ((unsigned long long)h22bits(hv) << 32) | sidx;
    }
    int cntu = fast ? degmax : max(cnt, __shfl_xor(cnt, 32, 64));  // uniform
    h2 ha0 = {(_Float16)0.f, (_Float16)0.f};
    h2 ha1 = ha0, ha2 = ha0, ha3 = ha0;
    const unsigned long long* cwp = cw[bwid][ns];
    int je = 0;
    while (je < cntu) {           // wave-uniform trip + granularity select
      if (cntu - je > 8) {
        gat_gather<HF, 8>(cwp, je, se, hb, ha0, ha1, ha2, ha3);
        je += 16;
      } else {
        gat_gather<HF, 4>(cwp, je, se, hb, ha0, ha1, ha2, ha3);
        je += 8;
      }
    }
    facc[0] += (float)ha0[0];
    facc[1] += (float)ha0[1];
    facc[2] += (float)ha1[0];
    facc[3] += (float)ha1[1];
    facc[4] += (float)ha2[0];
    facc[5] += (float)ha2[1];
    facc[6] += (float)ha3[0];
    facc[7] += (float)ha3[1];
  }
  // merge the 2 edge slots (within half), then deferred normalization
#pragma unroll
  for (int k = 0; k < 8; k++) facc[k] += __shfl_xor(facc[k], 16, 64);
  if (sl < 16) {
    float4 b0 = *(const float4*)(bias + fb);
    float4 b1 = *(const float4*)(bias + fb + 4);
    float v0 = facc[0] * fscale + b0.x, v1 = facc[1] * fscale + b0.y;
    float v2 = facc[2] * fscale + b0.z, v3 = facc[3] * fscale + b0.w;
    float v4 = facc[4] * fscale + b1.x, v5 = facc[5] * fscale + b1.y;
    float v6 = facc[6] * fscale + b1.z, v7 = facc[7] * fscale + b1.w;
    if (RELU) {
      v0 = fmaxf(v0, 0.f);
      v1 = fmaxf(v1, 0.f);
      v2 = fmaxf(v2, 0.f);
      v3 = fmaxf(v3, 0.f);
      v4 = fmaxf(v4, 0.f);
      v5 = fmaxf(v5, 0.f);
      v6 = fmaxf(v6, 0.f);
      v7 = fmaxf(v7, 0.f);
    }
    if constexpr (FP16OUT) {
      h2 p0, p1, p2, p3;
      p0[0] = (_Float16)v0;
      p0[1] = (_Float16)v1;
      p1[0] = (_Float16)v2;
      p1[1] = (_Float16)v3;
      p2[0] = (_Float16)v4;
      p2[1] = (_Float16)v5;
      p3[0] = (_Float16)v6;
      p3[1] = (_Float16)v7;
      uint4 o;
      o.x = h22bits(p0);
      o.y = h22bits(p1);
      o.z = h22bits(p2);
      o.w = h22bits(p3);
      *(uint4*)(outp + (size_t)node * HF + fb) = o;
    } else {
      *(float4*)(out + (size_t)node * HF + fb) = make_float4(v0, v1, v2, v3);
      *(float4*)(out + (size_t)node * HF + fb + 4) = make_float4(v4, v5, v6, v7);
    }
  }
}

// ---------------- masked global max pool (fp16 input) ----------------
__global__ void k_pool(const unsigned short* __restrict__ h,
                       const int* __restrict__ batch,
                       const int* __restrict__ mask, const int* __restrict__ flag,
                       unsigned* __restrict__ enc) {
  int f = threadIdx.x;  // 128 threads = 128 features
  int n0 = blockIdx.x * 32;
  if (n0 >= NN) return;
  int n1 = min(NN, n0 + 32);
  int any = *flag;
  float local = -1e30f;
  int curb = batch[n0];
  for (int n = n0; n < n1; ++n) {
    int b = batch[n];
    if (b != curb) {
      if (local > -1e30f) atomicMax(&enc[curb * 128 + f], encf(local));
      local = -1e30f;
      curb = b;
    }
    bool valid = (mask[n] == 0) || (!any);
    if (valid) local = fmaxf(local, u2f(h[(size_t)n * 128 + f]));
  }
  if (local > -1e30f) atomicMax(&enc[curb * 128 + f], encf(local));
}

__global__ void k_out(const unsigned* __restrict__ enc, float* __restrict__ out) {
  int i = blockIdx.x * blockDim.x + threadIdx.x;
  if (i < NBATCH * 128) out[i] = decf(enc[i]);
}

extern "C" void kernel_launch(void* const* d_in, const int* in_sizes, int n_in,
                              void* d_out, int out_size, void* d_ws, size_t ws_size,
                              hipStream_t stream) {
  const float* x = (const float*)d_in[0];
  const int* ei = (const int*)d_in[1];
  const int* batch = (const int*)d_in[2];
  const int* nmask = (const int*)d_in[3];
  // d_in[4] = edge_mask, unused
  const float* W1 = (const float*)d_in[5];
  const float* as1 = (const float*)d_in[6];
  const float* ad1 = (const float*)d_in[7];
  const float* b1 = (const float*)d_in[8];
  const float* W2 = (const float*)d_in[9];
  const float* as2 = (const float*)d_in[10];
  const float* ad2 = (const float*)d_in[11];
  const float* b2 = (const float*)d_in[12];
  const float* W3 = (const float*)d_in[13];
  const float* as3 = (const float*)d_in[14];
  const float* ad3 = (const float*)d_in[15];
  const float* b3 = (const float*)d_in[16];

  char* ws = (char*)d_ws;
  size_t off = 0;
  auto alloc = [&](size_t bytes) -> char* {
    char* p = ws + off;
    off = (off + bytes + 255) & ~(size_t)255;
    return p;
  };
  unsigned short* hA = (unsigned short*)alloc((size_t)MPAD * 512 * 2);  // 21 MB
  unsigned short* hG = (unsigned short*)alloc((size_t)MPAD * 512 * 2);  // 21 MB
  float* out3 = (float*)alloc((size_t)MPAD * 128 * 4);                  // 10.5 MB
  unsigned short* xP = (unsigned short*)out3;  // alias: xP dead before out3 written
  unsigned short* out3h = (unsigned short*)out3;  // fp16 layer-3 output (alias ok)
  unsigned short* wt1 = (unsigned short*)alloc((size_t)512 * 128 * 2);
  unsigned short* wt2 = (unsigned short*)alloc((size_t)512 * 512 * 2);
  unsigned short* wt3 = (unsigned short*)alloc((size_t)128 * 512 * 2);
  char* alStart = ws + off;
  float* alS1 = (float*)alloc((size_t)MPAD * 4 * 4);
  float* alD1 = (float*)alloc((size_t)MPAD * 4 * 4);
  float* alS2 = (float*)alloc((size_t)MPAD * 4 * 4);
  float* alD2 = (float*)alloc((size_t)MPAD * 4 * 4);
  float* alS3 = (float*)alloc((size_t)MPAD * 4);
  float* alD3 = (float*)alloc((size_t)MPAD * 4);
  int alcount = (int)(((ws + off) - alStart) / 4);
  int* deg = (int*)alloc((size_t)NN * 4);
  int* cursor = (int*)alloc((size_t)NN * 4);
  int* rowp = (int*)alloc((size_t)(NN + 1) * 4);
  int* colx = (int*)alloc((size_t)(NE + NN) * 4);
  unsigned* enc = (unsigned*)alloc((size_t)NBATCH * 128 * 4);
  int* flag = (int*)alloc(4);
  (void)ws_size; (void)n_in; (void)in_sizes; (void)out_size;

  k_init_prep<<<(PREPTOT + 255) / 256, 256, 0, stream>>>(
      W1, W2, W3, x, wt1, wt2, wt3, xP, deg, enc, flag, (float*)alStart, alcount);
  k_count<<<(NE + 255) / 256, 256, 0, stream>>>(ei, deg);
  k_scan<<<1, 1024, 0, stream>>>(deg, rowp, cursor);
  k_fill<<<(NE + NN + 255) / 256, 256, 0, stream>>>(ei, cursor, colx, nmask, flag);

  const int gemmBlocks = 4 * (MPAD / 128);  // 640, 1D swizzled
  dim3 gg3(1, MPAD / 64);
  const int aggBlocks = NN / 2;   // 10000: 8 nodes x 4 heads per block
  const int aggBlocks3 = NN / 8;  // 2500: 8 nodes per block, 1 head

  // Layer 1
  k_gemm<128, 256, true><<<gemmBlocks, 256, 0, stream>>>(
      xP, wt1, hA, as1, ad1, alS1, alD1, 128, 512, 4);
  k_agg<4, true, true, true><<<aggBlocks, 256, 0, stream>>>(
      hA, alS1, alD1, rowp, colx, b1, nullptr, hG);
  // Layer 2
  k_gemm<128, 256, true><<<gemmBlocks, 256, 0, stream>>>(
      hG, wt2, hA, as2, ad2, alS2, alD2, 512, 512, 4);
  k_agg<4, true, true, true><<<aggBlocks, 256, 0, stream>>>(
      hA, alS2, alD2, rowp, colx, b2, nullptr, hG);
  // Layer 3
  k_gemm<64, 128, false><<<gg3, 128, 0, stream>>>(hG, wt3, hA, as3, ad3, alS3,
                                                  alD3, 512, 128, 1);
  k_agg<1, false, true, false><<<aggBlocks3, 256, 0, stream>>>(
      hA, alS3, alD3, rowp, colx, b3, nullptr, out3h);

  // Masked global max pool
  k_pool<<<(NN + 31) / 32, 128, 0, stream>>>(out3h, batch, nmask, flag, enc);
  k_out<<<(NBATCH * 128 + 255) / 256, 256, 0, stream>>>(enc, (float*)d_out);
}

// Round 8
// 314.490 us; speedup vs baseline: 1.0061x; 1.0061x over previous
//
#include <hip/hip_runtime.h>
#include <stdint.h>

// GAT encoder: 3 GAT layers + masked global max pool.
// fp16-storage pipeline (threshold 2% relative; r16 absmax 9.8e-4).
// r17: GEMM 1D-grid XCD-affinity swizzle, launch_bounds(.,4), MPAD 20480.
// r18 FAILED (+43us): per-group runtime predication serialized gather issue.
// r19 WIN (-19us): uint4 gather, unconditional batches, wave-uniform {32,16}.
// r20 FAILED (+25us): 8-way switch bloated code, VGPR 32->44, occ 66->46.
// r21 FAILED (+9us): byte-offset LDS word broke addr-fold, VGPR 32->36.
// r22: revert to r19. r23 WIN (-12us, 314.8us): two nodes/wave in k_agg.
// r24 NEUTRAL (+1.6us): GEMM BK=64 — barrier-drain already hidden by
// wave-level overlap at 4 blocks/CU; doubled staging burst cancels gain.
// r25: revert GEMM to BK=32 (r23 exact, session best 314.8us).
// k_agg gather loop is codegen-fragile — do not perturb (r18/r20/r21).

#define NN 20000
#define MPAD 20480
#define NE 320000
#define NBATCH 16
#define NEG 0.2f
#define WSCALE 64.0f
#define WINV 0.015625f

using f16x8 = __attribute__((ext_vector_type(8))) _Float16;
using f32x4 = __attribute__((ext_vector_type(4))) float;
using h2 = __attribute__((ext_vector_type(2))) _Float16;

#define GLL16(gp, lp)                                                        \
  __builtin_amdgcn_global_load_lds(                                          \
      (const __attribute__((address_space(1))) void*)(gp),                   \
      (__attribute__((address_space(3))) void*)(lp), 16, 0, 0)

static __device__ __forceinline__ unsigned short h2u(_Float16 h) {
  union { _Float16 f; unsigned short u; } c;
  c.f = h;
  return c.u;
}
static __device__ __forceinline__ float u2f(unsigned short u) {
  union { unsigned short u; _Float16 f; } c;
  c.u = u;
  return (float)c.f;
}
static __device__ __forceinline__ h2 bits2h2(unsigned v) {
  union { unsigned u; h2 h; } c;
  c.u = v;
  return c.h;
}
static __device__ __forceinline__ unsigned h22bits(h2 h) {
  union { h2 h; unsigned u; } c;
  c.h = h;
  return c.u;
}
static __device__ __forceinline__ unsigned encf(float f) {
  unsigned u = __float_as_uint(f);
  return (u & 0x80000000u) ? ~u : (u | 0x80000000u);
}
static __device__ __forceinline__ float decf(unsigned u) {
  return __uint_as_float((u & 0x80000000u) ? (u ^ 0x80000000u) : ~u);
}

// -------- fused init+prep: deg/enc/flag/alpha-zero + W->fp16^T + x->fp16 ----
#define R1 (512 * 128)
#define R2 (512 * 512)
#define R3 (128 * 512)
#define PREPTOT (R1 + R2 + R3 + NN * 128)
__global__ void k_init_prep(const float* __restrict__ W1, const float* __restrict__ W2,
                            const float* __restrict__ W3, const float* __restrict__ x,
                            unsigned short* __restrict__ wt1,
                            unsigned short* __restrict__ wt2,
                            unsigned short* __restrict__ wt3,
                            unsigned short* __restrict__ xp, int* deg,
                            unsigned* enc, int* flag, float* alz, int alcount) {
  int idx = blockIdx.x * blockDim.x + threadIdx.x;
  if (idx < R1) {
    int n = idx & 511, k = idx >> 9;  // W1 [128][512]
    wt1[(size_t)n * 128 + k] = h2u((_Float16)(W1[(size_t)k * 512 + n] * WSCALE));
  } else if (idx < R1 + R2) {
    int j = idx - R1;
    int n = j & 511, k = j >> 9;  // W2 [512][512]
    wt2[(size_t)n * 512 + k] = h2u((_Float16)(W2[(size_t)k * 512 + n] * WSCALE));
  } else if (idx < R1 + R2 + R3) {
    int j = idx - (R1 + R2);
    int n = j & 127, k = j >> 7;  // W3 [512][128]
    wt3[(size_t)n * 512 + k] = h2u((_Float16)(W3[(size_t)k * 128 + n] * WSCALE));
  } else if (idx < PREPTOT) {
    int j = idx - (R1 + R2 + R3);
    xp[j] = h2u((_Float16)x[j]);
  }
  if (idx < NN) deg[idx] = 1;  // self loop
  if (idx < NBATCH * 128) enc[idx] = ~__float_as_uint(-1e30f);  // encf(-1e30)
  if (idx == 0) *flag = 0;
  if (idx < alcount) alz[idx] = 0.f;
}

__global__ void k_count(const int* __restrict__ ei, int* __restrict__ deg) {
  int e = blockIdx.x * blockDim.x + threadIdx.x;
  if (e < NE) atomicAdd(&deg[ei[NE + e]], 1);
}

__global__ void k_scan(const int* __restrict__ deg, int* __restrict__ row_ptr,
                       int* __restrict__ cursor) {
  __shared__ int wsum[16];
  int t = threadIdx.x;  // 1024 threads
  int lane = t & 63, wid = t >> 6;
  const int CH = 20;
  int beg = t * CH;
  int s = 0;
  for (int i = 0; i < CH; i++) {
    int idx = beg + i;
    if (idx < NN) s += deg[idx];
  }
  int incl = s;
  for (int off = 1; off < 64; off <<= 1) {
    int v = __shfl_up(incl, off, 64);
    if (lane >= off) incl += v;
  }
  if (lane == 63) wsum[wid] = incl;
  __syncthreads();
  if (t < 16) {
    int v = wsum[t];
    int in2 = v;
    for (int off = 1; off < 16; off <<= 1) {
      int u = __shfl_up(in2, off, 16);
      if (t >= off) in2 += u;
    }
    wsum[t] = in2 - v;  // exclusive wave base
  }
  __syncthreads();
  int run = wsum[wid] + incl - s;
  for (int i = 0; i < CH; i++) {
    int idx = beg + i;
    if (idx < NN) {
      row_ptr[idx] = run;
      cursor[idx] = run;
      run += deg[idx];
    }
  }
  if (t == 1023) row_ptr[NN] = run;
}

__global__ void k_fill(const int* __restrict__ ei, int* __restrict__ cursor,
                       int* __restrict__ col, const int* __restrict__ nmask,
                       int* __restrict__ flag) {
  int i = blockIdx.x * blockDim.x + threadIdx.x;
  if (i >= NE + NN) return;
  int src, dst;
  if (i < NE) {
    src = ei[i];
    dst = ei[NE + i];
  } else {
    src = dst = i - NE;
    if (nmask[src] != 0) *flag = 1;
  }
  int pos = atomicAdd(&cursor[dst], 1);
  col[pos] = src;
}

// ---------------- GEMM: fp16 x fp16 -> fp16 C, fp32 acc, alpha fused --------
// Swapped mfma operands: thread (lquad,lrow) reg r holds C[m=lrow][n=lquad*4+r].
// SWIZ: 1D grid, id%8 == (bm-block)%8 -> one XCD owns each A row-block (A
// fetched once into its L2; 4 bn-variants share it). Staging via
// global_load_lds width=16.
#define BN 128
#define BK 32

template <int BMT, int NT, bool SWIZ>
__global__ __launch_bounds__(NT, 4) void k_gemm(
    const unsigned short* __restrict__ Ap, const unsigned short* __restrict__ Wt,
    unsigned short* __restrict__ C, const float* __restrict__ attS,
    const float* __restrict__ attD, float* __restrict__ alS,
    float* __restrict__ alD, int K, int Nc, int H) {
  __shared__ __align__(16) unsigned short As[BMT][BK];
  __shared__ __align__(16) unsigned short Bs[BN][BK];
  int tid = threadIdx.x;
  int bm, bn;
  if constexpr (SWIZ) {
    int id = blockIdx.x;        // NBX=4: id = r + 8*(bn_i + 4*q), bm_row = q*8+r
    int r = id & 7, t = id >> 3;
    bn = (t & 3) * BN;
    bm = (((t >> 2) << 3) + r) * BMT;
  } else {
    bm = blockIdx.y * BMT;
    bn = blockIdx.x * BN;
  }
  int wid = tid >> 6, lane = tid & 63;
  int wm = (BMT == 128) ? (wid >> 1) * 64 : 0;
  int wn = (BMT == 128) ? (wid & 1) * 64 : wid * 64;
  int lrow = lane & 15, lquad = lane >> 4;

  f32x4 acc[4][4] = {};

  for (int k0 = 0; k0 < K; k0 += BK) {
    __syncthreads();
#pragma unroll
    for (int i = 0; i < (BMT * 4) / NT; i++) {
      int slot = tid + NT * i;
      int row = slot >> 2;
      int ks = (slot & 3) * 8;
      GLL16(Ap + (size_t)(bm + row) * K + k0 + ks, &As[0][0] + (size_t)slot * 8);
    }
#pragma unroll
    for (int i = 0; i < 512 / NT; i++) {
      int slot = tid + NT * i;
      int row = slot >> 2;
      int ks = (slot & 3) * 8;
      GLL16(Wt + (size_t)(bn + row) * K + k0 + ks, &Bs[0][0] + (size_t)slot * 8);
    }
    __syncthreads();

    f16x8 af[4];
#pragma unroll
    for (int mf = 0; mf < 4; mf++)
      af[mf] = *(const f16x8*)&As[wm + mf * 16 + lrow][lquad * 8];
#pragma unroll
    for (int nf = 0; nf < 4; nf++) {
      f16x8 bf = *(const f16x8*)&Bs[wn + nf * 16 + lrow][lquad * 8];
#pragma unroll
      for (int mf = 0; mf < 4; mf++)
        acc[mf][nf] =
            __builtin_amdgcn_mfma_f32_16x16x32_f16(bf, af[mf], acc[mf][nf], 0, 0, 0);
    }
  }
  // undo the x64 W scale
#pragma unroll
  for (int mf = 0; mf < 4; mf++)
#pragma unroll
    for (int nf = 0; nf < 4; nf++)
#pragma unroll
      for (int r = 0; r < 4; r++) acc[mf][nf][r] *= WINV;

  // fused alpha (this block's 128 cols == one head)
  float4 aS[4], aD[4];
#pragma unroll
  for (int nf = 0; nf < 4; nf++) {
    int n0 = bn + wn + nf * 16 + lquad * 4;
    aS[nf] = *(const float4*)(attS + n0);
    aD[nf] = *(const float4*)(attD + n0);
  }
  int head = bn >> 7;
#pragma unroll
  for (int mf = 0; mf < 4; mf++) {
    float ps = 0.f, pd = 0.f;
#pragma unroll
    for (int nf = 0; nf < 4; nf++) {
      ps += acc[mf][nf][0] * aS[nf].x + acc[mf][nf][1] * aS[nf].y +
            acc[mf][nf][2] * aS[nf].z + acc[mf][nf][3] * aS[nf].w;
      pd += acc[mf][nf][0] * aD[nf].x + acc[mf][nf][1] * aD[nf].y +
            acc[mf][nf][2] * aD[nf].z + acc[mf][nf][3] * aD[nf].w;
    }
    ps += __shfl_xor(ps, 16, 64);
    ps += __shfl_xor(ps, 32, 64);
    pd += __shfl_xor(pd, 16, 64);
    pd += __shfl_xor(pd, 32, 64);
    int row = bm + wm + mf * 16 + lrow;
    if (lquad == 0) {
      atomicAdd(&alS[(size_t)row * H + head], ps);
      atomicAdd(&alD[(size_t)row * H + head], pd);
    }
  }
  // C store: one 8B ushort4 per (mf,nf)
#pragma unroll
  for (int mf = 0; mf < 4; mf++) {
    int m = bm + wm + mf * 16 + lrow;
#pragma unroll
    for (int nf = 0; nf < 4; nf++) {
      int n0 = bn + wn + nf * 16 + lquad * 4;
      ushort4 o;
      o.x = h2u((_Float16)acc[mf][nf][0]);
      o.y = h2u((_Float16)acc[mf][nf][1]);
      o.z = h2u((_Float16)acc[mf][nf][2]);
      o.w = h2u((_Float16)acc[mf][nf][3]);
      *(ushort4*)(C + (size_t)m * Nc + n0) = o;
    }
  }
}

// Unconditional gather batch: NG groups of {2 edge slots x 2 node halves},
// uint4 per lane. LDS slots pre-zero-padded (32/node) so overshoot is safe.
// Structure kept identical to the proven r19 body (index-multiply address).
template <int HF, int NG>
static __device__ __forceinline__ void gat_gather(
    const unsigned long long* __restrict__ cwp, int je, int se,
    const unsigned short* __restrict__ hb, h2& ha0, h2& ha1, h2& ha2, h2& ha3) {
  unsigned long long q[NG];
  uint4 v[NG];
#pragma unroll
  for (int r = 0; r < NG; r++) q[r] = cwp[je + se + 2 * r];
#pragma unroll
  for (int r = 0; r < NG; r++)
    v[r] = *(const uint4*)(hb + (size_t)(unsigned)q[r] * HF);
#pragma unroll
  for (int r = 0; r < NG; r++) {
    h2 hw = bits2h2((unsigned)(q[r] >> 32));
    ha0 += hw * bits2h2(v[r].x);
    ha1 += hw * bits2h2(v[r].y);
    ha2 += hw * bits2h2(v[r].z);
    ha3 += hw * bits2h2(v[r].w);
  }
}

// ---------------- softmax + aggregate: 2 nodes/wave, 1 head/wave ------------
// PIN=true (H=4): sub = blockIdx&3 -> head s on XCDs {s, s+4}.
// Wave = 2 nodes x 1 head. Lanes: ns = lane>>5 (node half), sl = lane&31.
// Gather: 16 feature-lanes x uint4; 2 edge slots per node -> 4 loads/group.
// Wave-uniform two-tier granularity on cntu = max(cntA, cntB): 8 groups
// (16 edges/node) while rem>8, else 4 groups (8 edges/node); all batches
// unconditional. Fast path (both deg<=32): unnormalized t, scale by 1/S after
// the 2-slot merge. Reductions use xor offsets <=16 (stay within each half).
template <int H, bool RELU, bool FP16OUT, bool PIN>
__global__ __launch_bounds__(256) void k_agg(
    const unsigned short* __restrict__ h, const float* __restrict__ as_,
    const float* __restrict__ ad_, const int* __restrict__ row_ptr,
    const int* __restrict__ col, const float* __restrict__ bias,
    float* __restrict__ out, unsigned short* __restrict__ outp) {
  constexpr int HF = H * 128;
  __shared__ unsigned long long cw[4][2][32];
  int tid = threadIdx.x, bwid = tid >> 6, lane = tid & 63;
  int ns = lane >> 5, sl = lane & 31;
  int node, sub;
  if constexpr (PIN) {
    sub = blockIdx.x & 3;
    node = (blockIdx.x >> 2) * 8 + bwid * 2 + ns;  // grid = NN/2, NN%8==0
  } else {
    node = blockIdx.x * 8 + bwid * 2 + ns;  // grid = NN/8 exact
    sub = 0;
  }
  if (node >= NN) node = NN - 1;  // never taken (grids exact); keeps wave whole
  int beg = row_ptr[node], end = row_ptr[node + 1];
  int deg = end - beg;
  int degmax = max(deg, __shfl_xor(deg, 32, 64));  // wave-uniform
  bool fast = (degmax <= 32);
  float adv = ad_[(size_t)node * H + sub];
  float shift = (adv > 0.f) ? adv : NEG * adv;  // per-node surrogate max
  float fscale = 1.f;

  if (__builtin_expect(fast, 1)) {
    unsigned sidx = 0;
    float t = 0.f;
    if (sl < deg) {
      sidx = (unsigned)col[beg + sl];
      float e = as_[(size_t)sidx * H + sub] + adv;
      e = (e > 0.f) ? e : NEG * e;
      t = fminf(__expf(e - shift), 60000.f);  // f16-range guard
    }
    _Float16 ht = (_Float16)t;
    h2 hv;
    hv[0] = ht;
    hv[1] = ht;
    cw[bwid][ns][sl] = ((unsigned long long)h22bits(hv) << 32) | sidx;
    float S = t;  // per-half sum reduce (offsets <=16 stay within half)
#pragma unroll
    for (int off = 16; off; off >>= 1) S += __shfl_xor(S, off, 64);
    fscale = 1.f / S;
  }
  float Mr = 0.f, Sinv = 0.f;
  if (!fast) {  // rare general path: per-half online softmax
    float m = -1e30f, s = 0.f;
    for (int j = beg + sl; j < end; j += 32) {
      int sidx = col[j];
      float e = as_[(size_t)sidx * H + sub] + adv;
      e = (e > 0.f) ? e : NEG * e;
      float nm = fmaxf(m, e);
      s = s * __expf(m - nm) + __expf(e - nm);
      m = nm;
    }
    float mm = m;
#pragma unroll
    for (int off = 16; off; off >>= 1) mm = fmaxf(mm, __shfl_xor(mm, off, 64));
    float t = s * __expf(m - mm);
#pragma unroll
    for (int off = 16; off; off >>= 1) t += __shfl_xor(t, off, 64);
    Mr = mm;
    Sinv = 1.f / t;
  }

  const int se = (lane >> 4) & 1;                // edge slot 0..1 within node
  const int fb = sub * 128 + (lane & 15) * 8;    // 8 features/lane
  const unsigned short* __restrict__ hb = h + fb;
  float facc[8] = {0.f, 0.f, 0.f, 0.f, 0.f, 0.f, 0.f, 0.f};
  int nchunk = fast ? 1 : ((degmax + 31) >> 5);  // wave-uniform
  for (int ch = 0; ch < nchunk; ch++) {
    int c0 = beg + ch * 32;
    int cnt = end - c0;                 // per-half; may be <=0 when exhausted
    cnt = (cnt > 32) ? 32 : cnt;
    if (!fast) {  // refill normalized weights; zero-pad all 32 slots
      unsigned sidx = 0;
      float w = 0.f;
      if (sl < cnt) {
        sidx = (unsigned)col[c0 + sl];
        float e = as_[(size_t)sidx * H + sub] + adv;
        e = (e > 0.f) ? e : NEG * e;
        w = __expf(e - Mr) * Sinv;
      }
      _Float16 hw = (_Float16)w;
      h2 hv;
      hv[0] = hw;
      hv[1] = hw;
      cw[bwid][ns][sl] = ((unsigned long long)h22bits(hv) << 32) | sidx;
    }
    int cntu = fast ? degmax : max(cnt, __shfl_xor(cnt, 32, 64));  // uniform
    h2 ha0 = {(_Float16)0.f, (_Float16)0.f};
    h2 ha1 = ha0, ha2 = ha0, ha3 = ha0;
    const unsigned long long* cwp = cw[bwid][ns];
    int je = 0;
    while (je < cntu) {           // wave-uniform trip + granularity select
      if (cntu - je > 8) {
        gat_gather<HF, 8>(cwp, je, se, hb, ha0, ha1, ha2, ha3);
        je += 16;
      } else {
        gat_gather<HF, 4>(cwp, je, se, hb, ha0, ha1, ha2, ha3);
        je += 8;
      }
    }
    facc[0] += (float)ha0[0];
    facc[1] += (float)ha0[1];
    facc[2] += (float)ha1[0];
    facc[3] += (float)ha1[1];
    facc[4] += (float)ha2[0];
    facc[5] += (float)ha2[1];
    facc[6] += (float)ha3[0];
    facc[7] += (float)ha3[1];
  }
  // merge the 2 edge slots (within half), then deferred normalization
#pragma unroll
  for (int k = 0; k < 8; k++) facc[k] += __shfl_xor(facc[k], 16, 64);
  if (sl < 16) {
    float4 b0 = *(const float4*)(bias + fb);
    float4 b1 = *(const float4*)(bias + fb + 4);
    float v0 = facc[0] * fscale + b0.x, v1 = facc[1] * fscale + b0.y;
    float v2 = facc[2] * fscale + b0.z, v3 = facc[3] * fscale + b0.w;
    float v4 = facc[4] * fscale + b1.x, v5 = facc[5] * fscale + b1.y;
    float v6 = facc[6] * fscale + b1.z, v7 = facc[7] * fscale + b1.w;
    if (RELU) {
      v0 = fmaxf(v0, 0.f);
      v1 = fmaxf(v1, 0.f);
      v2 = fmaxf(v2, 0.f);
      v3 = fmaxf(v3, 0.f);
      v4 = fmaxf(v4, 0.f);
      v5 = fmaxf(v5, 0.f);
      v6 = fmaxf(v6, 0.f);
      v7 = fmaxf(v7, 0.f);
    }
    if constexpr (FP16OUT) {
      h2 p0, p1, p2, p3;
      p0[0] = (_Float16)v0;
      p0[1] = (_Float16)v1;
      p1[0] = (_Float16)v2;
      p1[1] = (_Float16)v3;
      p2[0] = (_Float16)v4;
      p2[1] = (_Float16)v5;
      p3[0] = (_Float16)v6;
      p3[1] = (_Float16)v7;
      uint4 o;
      o.x = h22bits(p0);
      o.y = h22bits(p1);
      o.z = h22bits(p2);
      o.w = h22bits(p3);
      *(uint4*)(outp + (size_t)node * HF + fb) = o;
    } else {
      *(float4*)(out + (size_t)node * HF + fb) = make_float4(v0, v1, v2, v3);
      *(float4*)(out + (size_t)node * HF + fb + 4) = make_float4(v4, v5, v6, v7);
    }
  }
}

// ---------------- masked global max pool (fp16 input) ----------------
__global__ void k_pool(const unsigned short* __restrict__ h,
                       const int* __restrict__ batch,
                       const int* __restrict__ mask, const int* __restrict__ flag,
                       unsigned* __restrict__ enc) {
  int f = threadIdx.x;  // 128 threads = 128 features
  int n0 = blockIdx.x * 32;
  if (n0 >= NN) return;
  int n1 = min(NN, n0 + 32);
  int any = *flag;
  float local = -1e30f;
  int curb = batch[n0];
  for (int n = n0; n < n1; ++n) {
    int b = batch[n];
    if (b != curb) {
      if (local > -1e30f) atomicMax(&enc[curb * 128 + f], encf(local));
      local = -1e30f;
      curb = b;
    }
    bool valid = (mask[n] == 0) || (!any);
    if (valid) local = fmaxf(local, u2f(h[(size_t)n * 128 + f]));
  }
  if (local > -1e30f) atomicMax(&enc[curb * 128 + f], encf(local));
}

__global__ void k_out(const unsigned* __restrict__ enc, float* __restrict__ out) {
  int i = blockIdx.x * blockDim.x + threadIdx.x;
  if (i < NBATCH * 128) out[i] = decf(enc[i]);
}

extern "C" void kernel_launch(void* const* d_in, const int* in_sizes, int n_in,
                              void* d_out, int out_size, void* d_ws, size_t ws_size,
                              hipStream_t stream) {
  const float* x = (const float*)d_in[0];
  const int* ei = (const int*)d_in[1];
  const int* batch = (const int*)d_in[2];
  const int* nmask = (const int*)d_in[3];
  // d_in[4] = edge_mask, unused
  const float* W1 = (const float*)d_in[5];
  const float* as1 = (const float*)d_in[6];
  const float* ad1 = (const float*)d_in[7];
  const float* b1 = (const float*)d_in[8];
  const float* W2 = (const float*)d_in[9];
  const float* as2 = (const float*)d_in[10];
  const float* ad2 = (const float*)d_in[11];
  const float* b2 = (const float*)d_in[12];
  const float* W3 = (const float*)d_in[13];
  const float* as3 = (const float*)d_in[14];
  const float* ad3 = (const float*)d_in[15];
  const float* b3 = (const float*)d_in[16];

  char* ws = (char*)d_ws;
  size_t off = 0;
  auto alloc = [&](size_t bytes) -> char* {
    char* p = ws + off;
    off = (off + bytes + 255) & ~(size_t)255;
    return p;
  };
  unsigned short* hA = (unsigned short*)alloc((size_t)MPAD * 512 * 2);  // 21 MB
  unsigned short* hG = (unsigned short*)alloc((size_t)MPAD * 512 * 2);  // 21 MB
  float* out3 = (float*)alloc((size_t)MPAD * 128 * 4);                  // 10.5 MB
  unsigned short* xP = (unsigned short*)out3;  // alias: xP dead before out3 written
  unsigned short* out3h = (unsigned short*)out3;  // fp16 layer-3 output (alias ok)
  unsigned short* wt1 = (unsigned short*)alloc((size_t)512 * 128 * 2);
  unsigned short* wt2 = (unsigned short*)alloc((size_t)512 * 512 * 2);
  unsigned short* wt3 = (unsigned short*)alloc((size_t)128 * 512 * 2);
  char* alStart = ws + off;
  float* alS1 = (float*)alloc((size_t)MPAD * 4 * 4);
  float* alD1 = (float*)alloc((size_t)MPAD * 4 * 4);
  float* alS2 = (float*)alloc((size_t)MPAD * 4 * 4);
  float* alD2 = (float*)alloc((size_t)MPAD * 4 * 4);
  float* alS3 = (float*)alloc((size_t)MPAD * 4);
  float* alD3 = (float*)alloc((size_t)MPAD * 4);
  int alcount = (int)(((ws + off) - alStart) / 4);
  int* deg = (int*)alloc((size_t)NN * 4);
  int* cursor = (int*)alloc((size_t)NN * 4);
  int* rowp = (int*)alloc((size_t)(NN + 1) * 4);
  int* colx = (int*)alloc((size_t)(NE + NN) * 4);
  unsigned* enc = (unsigned*)alloc((size_t)NBATCH * 128 * 4);
  int* flag = (int*)alloc(4);
  (void)ws_size; (void)n_in; (void)in_sizes; (void)out_size;

  k_init_prep<<<(PREPTOT + 255) / 256, 256, 0, stream>>>(
      W1, W2, W3, x, wt1, wt2, wt3, xP, deg, enc, flag, (float*)alStart, alcount);
  k_count<<<(NE + 255) / 256, 256, 0, stream>>>(ei, deg);
  k_scan<<<1, 1024, 0, stream>>>(deg, rowp, cursor);
  k_fill<<<(NE + NN + 255) / 256, 256, 0, stream>>>(ei, cursor, colx, nmask, flag);

  const int gemmBlocks = 4 * (MPAD / 128);  // 640, 1D swizzled
  dim3 gg3(1, MPAD / 64);
  const int aggBlocks = NN / 2;   // 10000: 8 nodes x 4 heads per block
  const int aggBlocks3 = NN / 8;  // 2500: 8 nodes per block, 1 head

  // Layer 1
  k_gemm<128, 256, true><<<gemmBlocks, 256, 0, stream>>>(
      xP, wt1, hA, as1, ad1, alS1, alD1, 128, 512, 4);
  k_agg<4, true, true, true><<<aggBlocks, 256, 0, stream>>>(
      hA, alS1, alD1, rowp, colx, b1, nullptr, hG);
  // Layer 2
  k_gemm<128, 256, true><<<gemmBlocks, 256, 0, stream>>>(
      hG, wt2, hA, as2, ad2, alS2, alD2, 512, 512, 4);
  k_agg<4, true, true, true><<<aggBlocks, 256, 0, stream>>>(
      hA, alS2, alD2, rowp, colx, b2, nullptr, hG);
  // Layer 3
  k_gemm<64, 128, false><<<gg3, 128, 0, stream>>>(hG, wt3, hA, as3, ad3, alS3,
                                                  alD3, 512, 128, 1);
  k_agg<1, false, true, false><<<aggBlocks3, 256, 0, stream>>>(
      hA, alS3, alD3, rowp, colx, b3, nullptr, out3h);

  // Masked global max pool
  k_pool<<<(NN + 31) / 32, 128, 0, stream>>>(out3h, batch, nmask, flag, enc);
  k_out<<<(NBATCH * 128 + 255) / 256, 256, 0, stream>>>(enc, (float*)d_out);
}